// Round 1
// baseline (641.423 us; speedup 1.0000x reference)
//
#include <hip/hip_runtime.h>
#include <math.h>

#define N_NODES 100000
#define N_EDGES 1600000
#define IN_F 512
#define HID 128
#define NCLS 7

#define DEG_SHIFT 43
#define DEG_WMASK ((1ull << 43) - 1)
#define DEG_SCALE 4194304.0f          // 2^22
#define DEG_INV_SCALE (1.0f / 4194304.0f)
#define NB_SCAN 98                    // ceil(100000 / 1024)

typedef short short8 __attribute__((ext_vector_type(8)));
typedef float f32x4 __attribute__((ext_vector_type(4)));

__device__ __forceinline__ unsigned pack_bf16x2(float a, float b) {
  unsigned ua = __float_as_uint(a), ub = __float_as_uint(b);
  unsigned ra = (ua + 0x7FFFu + ((ua >> 16) & 1u)) >> 16;     // RNE
  unsigned rb = (ub + 0x7FFFu + ((ub >> 16) & 1u)) >> 16;
  return ra | (rb << 16);
}
__device__ __forceinline__ unsigned short f32_to_bf16(float v) {
  unsigned u = __float_as_uint(v);
  return (unsigned short)((u + 0x7FFFu + ((u >> 16) & 1u)) >> 16);
}
__device__ __forceinline__ float bf_lo(unsigned u) { return __uint_as_float(u << 16); }
__device__ __forceinline__ float bf_hi(unsigned u) { return __uint_as_float(u & 0xFFFF0000u); }

// ---------------- degree accumulation: one u64 atomic per edge (count | fixed-point wsum) --------
__global__ void k_deg(const int* __restrict__ ei, const float* __restrict__ ew,
                      unsigned long long* __restrict__ packed) {
  int e = blockIdx.x * 256 + threadIdx.x;          // grid exact: N_EDGES % 256 == 0
  int d = ei[N_EDGES + e];
  unsigned long long fx = (unsigned long long)(ew[e] * DEG_SCALE + 0.5f);
  atomicAdd(&packed[d], (1ull << DEG_SHIFT) | fx);
}

// ---------------- merged: scan-partial + dinv/cnt  (blocks 0..NB_SCAN-1)  and W1 repack (32 more)
// W1 frag-major bf16 layout: w1bf[(s*8 + t)*64 + lane] (uint4), n = t*16+(lane&15),
// k = s*32 + (lane>>4)*8 + {0..7}. One B fragment = 1 KB fully contiguous, lane-ordered.
__global__ void k_mid(const unsigned long long* __restrict__ packed,
                      float* __restrict__ dinv, int* __restrict__ cnt, int* __restrict__ bsum,
                      const float* __restrict__ W1, uint4* __restrict__ w1bf,
                      uint2* __restrict__ csr_pad) {
  const int b = blockIdx.x, t = threadIdx.x;
  if (b >= NB_SCAN) {                              // ---- W1 repack part ----
    int idx = (b - NB_SCAN) * 256 + t;             // 0..8191
    if (idx < 8) csr_pad[idx] = make_uint2(0u, 0u);  // safe over-read entries (src=0, w=0)
    int lane = idx & 63;
    int st = idx >> 6;
    int tt = st & 7, ss = st >> 3;
    int n = tt * 16 + (lane & 15);
    int k0 = ss * 32 + (lane >> 4) * 8;
    uint4 v;
    v.x = pack_bf16x2(W1[(size_t)(k0 + 0) * HID + n], W1[(size_t)(k0 + 1) * HID + n]);
    v.y = pack_bf16x2(W1[(size_t)(k0 + 2) * HID + n], W1[(size_t)(k0 + 3) * HID + n]);
    v.z = pack_bf16x2(W1[(size_t)(k0 + 4) * HID + n], W1[(size_t)(k0 + 5) * HID + n]);
    v.w = pack_bf16x2(W1[(size_t)(k0 + 6) * HID + n], W1[(size_t)(k0 + 7) * HID + n]);
    w1bf[idx] = v;
    return;
  }
  // ---- dinv + cnt + per-block partial sum ----
  __shared__ int sh[256];
  int base = b * 1024;
  int v = 0;
#pragma unroll
  for (int q = 0; q < 4; q++) {
    int idx = base + t * 4 + q;
    if (idx < N_NODES) {
      unsigned long long p = packed[idx];
      int c = (int)(p >> DEG_SHIFT);
      cnt[idx] = c;
      dinv[idx] = rsqrtf((float)(p & DEG_WMASK) * DEG_INV_SCALE + 1.0f);  // +1 = self-loop
      v += c;
    }
  }
  sh[t] = v;
  __syncthreads();
  for (int o = 128; o > 0; o >>= 1) {
    if (t < o) sh[t] += sh[t + o];
    __syncthreads();
  }
  if (t == 0) bsum[b] = sh[0];
}

__global__ void k_scan_bsum(int* bsum, int nb) {
  if (threadIdx.x == 0 && blockIdx.x == 0) {
    int acc = 0;
    for (int i = 0; i < nb; i++) { int v = bsum[i]; bsum[i] = acc; acc += v; }
  }
}

// exclusive scan -> offs; also writes a second copy (cursor) that k_fill bumps atomically.
__global__ void k_scan_final(const int* __restrict__ cnt, const int* __restrict__ bsum,
                             int* __restrict__ offs, int* __restrict__ cursor) {
  __shared__ int s[256];
  int t = threadIdx.x;
  int base = blockIdx.x * 1024;
  int v[4]; int sum = 0;
#pragma unroll
  for (int q = 0; q < 4; q++) {
    int idx = base + t * 4 + q;
    v[q] = (idx < N_NODES) ? cnt[idx] : 0;
    sum += v[q];
  }
  s[t] = sum;
  __syncthreads();
  for (int o = 1; o < 256; o <<= 1) {
    int x = (t >= o) ? s[t - o] : 0;
    __syncthreads();
    s[t] += x;
    __syncthreads();
  }
  int acc = s[t] - sum + bsum[blockIdx.x];
#pragma unroll
  for (int q = 0; q < 4; q++) {
    int idx = base + t * 4 + q;
    if (idx < N_NODES) { offs[idx] = acc; cursor[idx] = acc; }
    acc += v[q];
  }
}

// ---------------- CSR fill: cursor atomics replace the rank[] round-trip ----------------
// After this kernel, cursor[i] == offs[i] + cnt[i] == end[i]  (used directly by the aggs).
__global__ void k_fill(const int* __restrict__ ei, const float* __restrict__ ew,
                       int* __restrict__ cursor, uint2* __restrict__ csr) {
  int e = blockIdx.x * 256 + threadIdx.x;          // grid exact
  int s = ei[e];
  int d = ei[N_EDGES + e];
  int p = atomicAdd(&cursor[d], 1);
  csr[p] = make_uint2((unsigned)s, __float_as_uint(ew[e]));
}

// ---------------- GEMM1: wave = 16 rows x 128 cols, K=512; A direct from global (no LDS) --------
// Per k-step s: lane reads 8 consecutive f32 of row (lane&15) at k = s*32 + (lane>>4)*8
// -> per wave: 16 rows x 128 B contiguous, perfectly coalesced, each element read once.
__global__ __launch_bounds__(256) void k_gemm1(const float* __restrict__ x,
                                               const uint4* __restrict__ w1bf,
                                               const float* __restrict__ dinv,
                                               unsigned short* __restrict__ h_u16) {
  const int tid = threadIdx.x;
  const int lane = tid & 63;
  const int wv = tid >> 6;
  const int gw = blockIdx.x * 4 + wv;
  if (gw >= N_NODES / 16) return;
  const int m0 = gw * 16;
  const int l16 = lane & 15, quad = lane >> 4;
  const float* arow = x + (size_t)(m0 + l16) * IN_F + quad * 8;

  f32x4 acc[8];
#pragma unroll
  for (int t = 0; t < 8; t++) acc[t] = (f32x4){0.f, 0.f, 0.f, 0.f};

#pragma unroll
  for (int ks = 0; ks < 16; ks++) {
    const float* ap = arow + ks * 32;
    float4 a0 = *(const float4*)ap;
    float4 a1 = *(const float4*)(ap + 4);
    uint4 au;
    au.x = pack_bf16x2(a0.x, a0.y);
    au.y = pack_bf16x2(a0.z, a0.w);
    au.z = pack_bf16x2(a1.x, a1.y);
    au.w = pack_bf16x2(a1.z, a1.w);
    short8 af = *(short8*)&au;
    const uint4* bbase = w1bf + (size_t)ks * 8 * 64 + lane;   // L2-resident 128 KB
#pragma unroll
    for (int t = 0; t < 8; t++) {
      uint4 bv = bbase[t * 64];
      acc[t] = __builtin_amdgcn_mfma_f32_16x16x32_bf16(af, *(const short8*)&bv,
                                                       acc[t], 0, 0, 0);
    }
  }
  // epilogue: C/D row = quad*4+r, col = t*16+l16; scale by dinv[row], store bf16
  float df[4];
#pragma unroll
  for (int r = 0; r < 4; r++) df[r] = dinv[m0 + quad * 4 + r];
#pragma unroll
  for (int t = 0; t < 8; t++)
#pragma unroll
    for (int r = 0; r < 4; r++)
      h_u16[(size_t)(m0 + quad * 4 + r) * HID + t * 16 + l16] = f32_to_bf16(acc[t][r] * df[r]);
}

// ---------------- layer-1 aggregation + ELU + FUSED GEMM2 (act1 never materialized) -------------
// Wave per node. Lane covers feats [2l, 2l+1]. After ELU, 7 per-lane partials vs register W2,
// 6-step butterfly, lanes 0..7 store the 32 B h2 row (pre-scaled by dinv[i], pad = 0).
__global__ __launch_bounds__(256) void k_agg1(const unsigned* __restrict__ h_u,
    const float* __restrict__ dinv, const int* __restrict__ offs, const int* __restrict__ ends,
    const uint2* __restrict__ csr, const float* __restrict__ b1,
    const float* __restrict__ W2, float* __restrict__ h2) {
  int i = blockIdx.x * 4 + (threadIdx.x >> 6);
  int lane = threadIdx.x & 63;
  if (i >= N_NODES) return;
  float w2a[NCLS], w2b[NCLS];                      // 14 floats, L1-resident after warm-up
#pragma unroll
  for (int c = 0; c < NCLS; c++) {
    w2a[c] = W2[(size_t)(2 * lane) * NCLS + c];
    w2b[c] = W2[(size_t)(2 * lane + 1) * NCLS + c];
  }
  int start = offs[i], end = ends[i];
  float ax = 0.f, ay = 0.f;
  for (int p = start; p < end; p += 8) {
    uint2 e[8];
#pragma unroll
    for (int k = 0; k < 8; k++) e[k] = csr[p + k];   // padded: safe over-read
    unsigned u[8];
#pragma unroll
    for (int k = 0; k < 8; k++) u[k] = h_u[(size_t)e[k].x * 64 + lane];
#pragma unroll
    for (int k = 0; k < 8; k++) {
      float n = (k == 0 || p + k < end) ? __uint_as_float(e[k].y) : 0.f;
      ax = fmaf(bf_lo(u[k]), n, ax);
      ay = fmaf(bf_hi(u[k]), n, ay);
    }
  }
  float di = dinv[i];
  unsigned u = h_u[(size_t)i * 64 + lane];         // self (already * dinv[i])
  float2 bb = *(const float2*)(b1 + lane * 2);
  float vx = fmaf(di, ax + bf_lo(u), bb.x);
  float vy = fmaf(di, ay + bf_hi(u), bb.y);
  vx = vx > 0.f ? vx : expm1f(vx);                 // ELU (alpha=1)
  vy = vy > 0.f ? vy : expm1f(vy);
  // fused GEMM2: h2[i,:] = dinv[i] * (act1[i,:] @ W2)
  float s[NCLS];
#pragma unroll
  for (int c = 0; c < NCLS; c++) s[c] = fmaf(vy, w2b[c], vx * w2a[c]);
#pragma unroll
  for (int m = 1; m < 64; m <<= 1) {
#pragma unroll
    for (int c = 0; c < NCLS; c++) s[c] += __shfl_xor(s[c], m);
  }
  if (lane < 8) {
    float v = lane == 0 ? s[0] : lane == 1 ? s[1] : lane == 2 ? s[2] :
              lane == 3 ? s[3] : lane == 4 ? s[4] : lane == 5 ? s[5] : s[6];
    h2[(size_t)i * 8 + lane] = (lane < NCLS) ? v * di : 0.f;   // pad col = 0
  }
}

// ---------------- layer-2 aggregation + bias + log_softmax: wave per node (no divergence) -------
// Lane = (k = lane>>3 edge slot, f = lane&7 feature). 8 edges in flight per iteration.
__global__ __launch_bounds__(256) void k_agg2(const float* __restrict__ h2,
    const float* __restrict__ dinv, const int* __restrict__ offs, const int* __restrict__ ends,
    const uint2* __restrict__ csr, const float* __restrict__ b2, float* __restrict__ out) {
  int i = blockIdx.x * 4 + (threadIdx.x >> 6);
  int lane = threadIdx.x & 63;
  if (i >= N_NODES) return;
  int k = lane >> 3, f = lane & 7;
  int start = offs[i], end = ends[i];
  float acc = 0.f;
  for (int p = start; p < end; p += 8) {
    uint2 e = csr[p + k];                          // 8 lanes/address, padded tail safe
    float n = (p + k < end) ? __uint_as_float(e.y) : 0.f;
    acc = fmaf(h2[(size_t)e.x * 8 + f], n, acc);   // 32 B contiguous per edge
  }
  acc += __shfl_xor(acc, 8);                       // reduce over k
  acc += __shfl_xor(acc, 16);
  acc += __shfl_xor(acc, 32);
  float di = dinv[i];
  float v = fmaf(di, acc + h2[(size_t)i * 8 + f], (f < NCLS) ? b2[f] : 0.f);
  float vm = (f < NCLS) ? v : -INFINITY;
  vm = fmaxf(vm, __shfl_xor(vm, 1));
  vm = fmaxf(vm, __shfl_xor(vm, 2));
  vm = fmaxf(vm, __shfl_xor(vm, 4));
  float ex = (f < NCLS) ? expf(v - vm) : 0.f;
  float s8 = ex;
  s8 += __shfl_xor(s8, 1);
  s8 += __shfl_xor(s8, 2);
  s8 += __shfl_xor(s8, 4);
  float lse = logf(s8);
  if (k == 0 && f < NCLS) out[(size_t)i * NCLS + f] = v - vm - lse;
}

// ---------------- launch ----------------
extern "C" void kernel_launch(void* const* d_in, const int* in_sizes, int n_in,
                              void* d_out, int out_size, void* d_ws, size_t ws_size,
                              hipStream_t stream) {
  const float* x  = (const float*)d_in[0];
  const int*   ei = (const int*)d_in[1];
  const float* ew = (const float*)d_in[2];
  const float* W1 = (const float*)d_in[3];
  const float* b1 = (const float*)d_in[4];
  const float* W2 = (const float*)d_in[5];
  const float* b2 = (const float*)d_in[6];
  float* out = (float*)d_out;

  char* w = (char*)d_ws;
  const size_t Npad  = ((size_t)N_NODES * 4 + 255) & ~(size_t)255;
  const size_t Npad8 = ((size_t)N_NODES * 8 + 255) & ~(size_t)255;
  size_t off = 0;
  unsigned long long* packed = (unsigned long long*)(w + off); off += Npad8;  // zeroed
  float*    dinv     = (float*)(w + off);    off += Npad;
  int*      cnt      = (int*)(w + off);      off += Npad;
  int*      offs     = (int*)(w + off);      off += Npad;
  int*      cursor   = (int*)(w + off);      off += Npad;   // fill bumps; becomes end[]
  int*      bsum     = (int*)(w + off);      off += 1024;
  uint2*    csr      = (uint2*)(w + off);    off += ((size_t)(N_EDGES + 8) * 8 + 255) & ~(size_t)255;
  uint4*    w1bf     = (uint4*)(w + off);    off += (size_t)8192 * 16;        // 128 KB
  unsigned short* h_u16 = (unsigned short*)(w + off); off += (size_t)N_NODES * HID * 2;
  float*    h2       = (float*)(w + off);    off += (size_t)N_NODES * 8 * 4;

  hipMemsetAsync(packed, 0, Npad8, stream);

  k_deg<<<N_EDGES / 256, 256, 0, stream>>>(ei, ew, packed);
  k_mid<<<NB_SCAN + 32, 256, 0, stream>>>(packed, dinv, cnt, bsum, W1, w1bf, csr + N_EDGES);
  k_scan_bsum<<<1, 64, 0, stream>>>(bsum, NB_SCAN);
  k_scan_final<<<NB_SCAN, 256, 0, stream>>>(cnt, bsum, offs, cursor);
  k_fill<<<N_EDGES / 256, 256, 0, stream>>>(ei, ew, cursor, csr);
  k_gemm1<<<(N_NODES / 16 + 3) / 4, 256, 0, stream>>>(x, w1bf, dinv, h_u16);
  k_agg1<<<(N_NODES + 3) / 4, 256, 0, stream>>>((const unsigned*)h_u16, dinv, offs, cursor,
                                                csr, b1, W2, h2);
  k_agg2<<<(N_NODES + 3) / 4, 256, 0, stream>>>(h2, dinv, offs, cursor, csr, b2, out);
}

// Round 2
// 610.621 us; speedup vs baseline: 1.0504x; 1.0504x over previous
//
#include <hip/hip_runtime.h>
#include <math.h>

#define N_NODES 100000
#define N_EDGES 1600000
#define IN_F 512
#define HID 128
#define NCLS 7

#define DEG_SHIFT 43
#define DEG_WMASK ((1ull << 43) - 1)
#define DEG_SCALE 4194304.0f          // 2^22
#define DEG_INV_SCALE (1.0f / 4194304.0f)
#define NB_SCAN 98                    // ceil(100000 / 1024)

typedef short short8 __attribute__((ext_vector_type(8)));
typedef float f32x4 __attribute__((ext_vector_type(4)));
typedef unsigned long long u64;

__device__ __forceinline__ unsigned pack_bf16x2(float a, float b) {
  unsigned ua = __float_as_uint(a), ub = __float_as_uint(b);
  unsigned ra = (ua + 0x7FFFu + ((ua >> 16) & 1u)) >> 16;     // RNE
  unsigned rb = (ub + 0x7FFFu + ((ub >> 16) & 1u)) >> 16;
  return ra | (rb << 16);
}
__device__ __forceinline__ unsigned short f32_to_bf16(float v) {
  unsigned u = __float_as_uint(v);
  return (unsigned short)((u + 0x7FFFu + ((u >> 16) & 1u)) >> 16);
}
__device__ __forceinline__ float bf_lo(unsigned u) { return __uint_as_float(u << 16); }
__device__ __forceinline__ float bf_hi(unsigned u) { return __uint_as_float(u & 0xFFFF0000u); }

// ---------------- degree + count + rank in ONE u64 atomic per edge ----------------
// Streaming reads are non-temporal (evict-first): keeps the 800 KB `packed` atomic
// working set resident in L2.
__global__ void k_deg(const int* __restrict__ ei, const float* __restrict__ ew,
                      unsigned long long* __restrict__ packed, int* __restrict__ rank) {
  int e = blockIdx.x * 256 + threadIdx.x;          // grid exact: N_EDGES % 256 == 0
  int d = __builtin_nontemporal_load(ei + N_EDGES + e);
  float w = __builtin_nontemporal_load(ew + e);
  u64 fx = (u64)(w * DEG_SCALE + 0.5f);
  u64 old = atomicAdd(&packed[d], (1ull << DEG_SHIFT) | fx);
  __builtin_nontemporal_store((int)(old >> DEG_SHIFT), rank + e);  // slot within dst bucket
}

// ---------------- merged: scan-partial + dinv/cnt  (blocks 0..NB_SCAN-1)  and W1 repack (32 more)
// W1 frag-major bf16 layout: w1bf[(s*8 + t)*64 + lane] (uint4), n = t*16+(lane&15),
// k = s*32 + (lane>>4)*8 + {0..7}. One B fragment = 1 KB fully contiguous, lane-ordered.
__global__ void k_mid(const unsigned long long* __restrict__ packed,
                      float* __restrict__ dinv, int* __restrict__ cnt, int* __restrict__ bsum,
                      const float* __restrict__ W1, uint4* __restrict__ w1bf,
                      uint2* __restrict__ csr_pad) {
  const int b = blockIdx.x, t = threadIdx.x;
  if (b >= NB_SCAN) {                              // ---- W1 repack part ----
    int idx = (b - NB_SCAN) * 256 + t;             // 0..8191
    if (idx < 8) csr_pad[idx] = make_uint2(0u, 0u);  // safe over-read entries (src=0, w=0)
    int lane = idx & 63;
    int st = idx >> 6;
    int tt = st & 7, ss = st >> 3;
    int n = tt * 16 + (lane & 15);
    int k0 = ss * 32 + (lane >> 4) * 8;
    uint4 v;
    v.x = pack_bf16x2(W1[(size_t)(k0 + 0) * HID + n], W1[(size_t)(k0 + 1) * HID + n]);
    v.y = pack_bf16x2(W1[(size_t)(k0 + 2) * HID + n], W1[(size_t)(k0 + 3) * HID + n]);
    v.z = pack_bf16x2(W1[(size_t)(k0 + 4) * HID + n], W1[(size_t)(k0 + 5) * HID + n]);
    v.w = pack_bf16x2(W1[(size_t)(k0 + 6) * HID + n], W1[(size_t)(k0 + 7) * HID + n]);
    w1bf[idx] = v;
    return;
  }
  // ---- dinv + cnt + per-block partial sum ----
  __shared__ int sh[256];
  int base = b * 1024;
  int v = 0;
#pragma unroll
  for (int q = 0; q < 4; q++) {
    int idx = base + t * 4 + q;
    if (idx < N_NODES) {
      unsigned long long p = packed[idx];
      int c = (int)(p >> DEG_SHIFT);
      cnt[idx] = c;
      dinv[idx] = rsqrtf((float)(p & DEG_WMASK) * DEG_INV_SCALE + 1.0f);  // +1 = self-loop
      v += c;
    }
  }
  sh[t] = v;
  __syncthreads();
  for (int o = 128; o > 0; o >>= 1) {
    if (t < o) sh[t] += sh[t + o];
    __syncthreads();
  }
  if (t == 0) bsum[b] = sh[0];
}

__global__ void k_scan_bsum(int* bsum, int nb) {
  if (threadIdx.x == 0 && blockIdx.x == 0) {
    int acc = 0;
    for (int i = 0; i < nb; i++) { int v = bsum[i]; bsum[i] = acc; acc += v; }
  }
}

__global__ void k_scan_final(const int* __restrict__ cnt, const int* __restrict__ bsum,
                             int* __restrict__ offs) {
  __shared__ int s[256];
  int t = threadIdx.x;
  int base = blockIdx.x * 1024;
  int v[4]; int sum = 0;
#pragma unroll
  for (int q = 0; q < 4; q++) {
    int idx = base + t * 4 + q;
    v[q] = (idx < N_NODES) ? cnt[idx] : 0;
    sum += v[q];
  }
  s[t] = sum;
  __syncthreads();
  for (int o = 1; o < 256; o <<= 1) {
    int x = (t >= o) ? s[t - o] : 0;
    __syncthreads();
    s[t] += x;
    __syncthreads();
  }
  int acc = s[t] - sum + bsum[blockIdx.x];
#pragma unroll
  for (int q = 0; q < 4; q++) {
    int idx = base + t * 4 + q;
    if (idx < N_NODES) offs[idx] = acc;
    acc += v[q];
  }
}

// ---------------- CSR fill: NO atomics (rank from k_deg); nt streams protect csr L2 lines ------
// csr dirty lines (12.8 MB, ~1.6 MB/XCD slice) must stay in L2 long enough to absorb all
// ~8 writes per line; nt on the 25 MB of streaming reads stops them evicting those lines.
__global__ void k_fill(const int* __restrict__ ei, const float* __restrict__ ew,
                       const int* __restrict__ rank, const int* __restrict__ offs,
                       uint2* __restrict__ csr) {
  int e = blockIdx.x * 256 + threadIdx.x;          // grid exact
  int s = __builtin_nontemporal_load(ei + e);
  int d = __builtin_nontemporal_load(ei + N_EDGES + e);
  float w = __builtin_nontemporal_load(ew + e);
  int r = __builtin_nontemporal_load(rank + e);
  int p = offs[d] + r;                             // offs: 400 KB, cached (16x reuse)
  csr[p] = make_uint2((unsigned)s, __float_as_uint(w));   // normal store: wants L2 coalescing
}

// ---------------- GEMM1: wave = 16 rows x 128 cols, K=512; A direct from global (no LDS) --------
// Per k-step s: lane reads 8 consecutive f32 of row (lane&15) at k = s*32 + (lane>>4)*8
// -> per wave: 16 rows x 128 B contiguous, perfectly coalesced, each element read once (nt).
__global__ __launch_bounds__(256) void k_gemm1(const float* __restrict__ x,
                                               const uint4* __restrict__ w1bf,
                                               const float* __restrict__ dinv,
                                               unsigned short* __restrict__ h_u16) {
  const int tid = threadIdx.x;
  const int lane = tid & 63;
  const int wv = tid >> 6;
  const int gw = blockIdx.x * 4 + wv;
  if (gw >= N_NODES / 16) return;
  const int m0 = gw * 16;
  const int l16 = lane & 15, quad = lane >> 4;
  const float* arow = x + (size_t)(m0 + l16) * IN_F + quad * 8;

  f32x4 acc[8];
#pragma unroll
  for (int t = 0; t < 8; t++) acc[t] = (f32x4){0.f, 0.f, 0.f, 0.f};

#pragma unroll
  for (int ks = 0; ks < 16; ks++) {
    const float* ap = arow + ks * 32;
    f32x4 a0 = __builtin_nontemporal_load((const f32x4*)ap);        // read-once stream
    f32x4 a1 = __builtin_nontemporal_load((const f32x4*)(ap + 4));
    uint4 au;
    au.x = pack_bf16x2(a0[0], a0[1]);
    au.y = pack_bf16x2(a0[2], a0[3]);
    au.z = pack_bf16x2(a1[0], a1[1]);
    au.w = pack_bf16x2(a1[2], a1[3]);
    short8 af = *(short8*)&au;
    const uint4* bbase = w1bf + (size_t)ks * 8 * 64 + lane;         // L2-resident 128 KB
#pragma unroll
    for (int t = 0; t < 8; t++) {
      uint4 bv = bbase[t * 64];
      acc[t] = __builtin_amdgcn_mfma_f32_16x16x32_bf16(af, *(const short8*)&bv,
                                                       acc[t], 0, 0, 0);
    }
  }
  // epilogue: C/D row = quad*4+r, col = t*16+l16; scale by dinv[row], store bf16
  float df[4];
#pragma unroll
  for (int r = 0; r < 4; r++) df[r] = dinv[m0 + quad * 4 + r];
#pragma unroll
  for (int t = 0; t < 8; t++)
#pragma unroll
    for (int r = 0; r < 4; r++)
      h_u16[(size_t)(m0 + quad * 4 + r) * HID + t * 16 + l16] = f32_to_bf16(acc[t][r] * df[r]);
}

// ---------------- layer-1 aggregation + ELU + FUSED GEMM2 (act1 never materialized) -------------
// Wave per node. Lane covers feats [2l, 2l+1]. After ELU, 7 per-lane partials vs register W2,
// 6-step butterfly, lanes 0..7 store the 32 B h2 row (pre-scaled by dinv[i], pad = 0).
// csr reads are nt: the 12.8 MB stream must not evict the 25.6 MB h-row gather set from L2.
__global__ __launch_bounds__(256) void k_agg1(const unsigned* __restrict__ h_u,
    const float* __restrict__ dinv, const int* __restrict__ offs, const int* __restrict__ cnt,
    const uint2* __restrict__ csr, const float* __restrict__ b1,
    const float* __restrict__ W2, float* __restrict__ h2) {
  int i = blockIdx.x * 4 + (threadIdx.x >> 6);
  int lane = threadIdx.x & 63;
  if (i >= N_NODES) return;
  float w2a[NCLS], w2b[NCLS];                      // 14 floats, L1-resident after warm-up
#pragma unroll
  for (int c = 0; c < NCLS; c++) {
    w2a[c] = W2[(size_t)(2 * lane) * NCLS + c];
    w2b[c] = W2[(size_t)(2 * lane + 1) * NCLS + c];
  }
  int start = offs[i], end = start + cnt[i];
  float ax = 0.f, ay = 0.f;
  for (int p = start; p < end; p += 8) {
    u64 e[8];
#pragma unroll
    for (int k = 0; k < 8; k++)
      e[k] = __builtin_nontemporal_load((const u64*)(csr + p + k));  // padded: safe over-read
    unsigned u[8];
#pragma unroll
    for (int k = 0; k < 8; k++) u[k] = h_u[(size_t)(unsigned)e[k] * 64 + lane];
#pragma unroll
    for (int k = 0; k < 8; k++) {
      float n = (k == 0 || p + k < end) ? __uint_as_float((unsigned)(e[k] >> 32)) : 0.f;
      ax = fmaf(bf_lo(u[k]), n, ax);
      ay = fmaf(bf_hi(u[k]), n, ay);
    }
  }
  float di = dinv[i];
  unsigned u = h_u[(size_t)i * 64 + lane];         // self (already * dinv[i])
  float2 bb = *(const float2*)(b1 + lane * 2);
  float vx = fmaf(di, ax + bf_lo(u), bb.x);
  float vy = fmaf(di, ay + bf_hi(u), bb.y);
  vx = vx > 0.f ? vx : expm1f(vx);                 // ELU (alpha=1)
  vy = vy > 0.f ? vy : expm1f(vy);
  // fused GEMM2: h2[i,:] = dinv[i] * (act1[i,:] @ W2)
  float s[NCLS];
#pragma unroll
  for (int c = 0; c < NCLS; c++) s[c] = fmaf(vy, w2b[c], vx * w2a[c]);
#pragma unroll
  for (int m = 1; m < 64; m <<= 1) {
#pragma unroll
    for (int c = 0; c < NCLS; c++) s[c] += __shfl_xor(s[c], m);
  }
  if (lane < 8) {
    float v = lane == 0 ? s[0] : lane == 1 ? s[1] : lane == 2 ? s[2] :
              lane == 3 ? s[3] : lane == 4 ? s[4] : lane == 5 ? s[5] : s[6];
    h2[(size_t)i * 8 + lane] = (lane < NCLS) ? v * di : 0.f;   // pad col = 0
  }
}

// ---------------- layer-2 aggregation + bias + log_softmax: wave per node (no divergence) -------
// Lane = (k = lane>>3 edge slot, f = lane&7 feature). 8 edges in flight per iteration.
__global__ __launch_bounds__(256) void k_agg2(const float* __restrict__ h2,
    const float* __restrict__ dinv, const int* __restrict__ offs, const int* __restrict__ cnt,
    const uint2* __restrict__ csr, const float* __restrict__ b2, float* __restrict__ out) {
  int i = blockIdx.x * 4 + (threadIdx.x >> 6);
  int lane = threadIdx.x & 63;
  if (i >= N_NODES) return;
  int k = lane >> 3, f = lane & 7;
  int start = offs[i], end = start + cnt[i];
  float acc = 0.f;
  for (int p = start; p < end; p += 8) {
    u64 e = __builtin_nontemporal_load((const u64*)(csr + p + k));  // padded tail safe
    float n = (p + k < end) ? __uint_as_float((unsigned)(e >> 32)) : 0.f;
    acc = fmaf(h2[(size_t)(unsigned)e * 8 + f], n, acc);  // h2 3.2 MB: L2-resident gather
  }
  acc += __shfl_xor(acc, 8);                       // reduce over k
  acc += __shfl_xor(acc, 16);
  acc += __shfl_xor(acc, 32);
  float di = dinv[i];
  float v = fmaf(di, acc + h2[(size_t)i * 8 + f], (f < NCLS) ? b2[f] : 0.f);
  float vm = (f < NCLS) ? v : -INFINITY;
  vm = fmaxf(vm, __shfl_xor(vm, 1));
  vm = fmaxf(vm, __shfl_xor(vm, 2));
  vm = fmaxf(vm, __shfl_xor(vm, 4));
  float ex = (f < NCLS) ? expf(v - vm) : 0.f;
  float s8 = ex;
  s8 += __shfl_xor(s8, 1);
  s8 += __shfl_xor(s8, 2);
  s8 += __shfl_xor(s8, 4);
  float lse = logf(s8);
  if (k == 0 && f < NCLS) out[(size_t)i * NCLS + f] = v - vm - lse;
}

// ---------------- launch ----------------
extern "C" void kernel_launch(void* const* d_in, const int* in_sizes, int n_in,
                              void* d_out, int out_size, void* d_ws, size_t ws_size,
                              hipStream_t stream) {
  const float* x  = (const float*)d_in[0];
  const int*   ei = (const int*)d_in[1];
  const float* ew = (const float*)d_in[2];
  const float* W1 = (const float*)d_in[3];
  const float* b1 = (const float*)d_in[4];
  const float* W2 = (const float*)d_in[5];
  const float* b2 = (const float*)d_in[6];
  float* out = (float*)d_out;

  char* w = (char*)d_ws;
  const size_t Npad  = ((size_t)N_NODES * 4 + 255) & ~(size_t)255;
  const size_t Npad8 = ((size_t)N_NODES * 8 + 255) & ~(size_t)255;
  const size_t Epad  = ((size_t)N_EDGES * 4 + 255) & ~(size_t)255;
  size_t off = 0;
  unsigned long long* packed = (unsigned long long*)(w + off); off += Npad8;  // zeroed
  float*    dinv     = (float*)(w + off);    off += Npad;
  int*      cnt      = (int*)(w + off);      off += Npad;
  int*      offs     = (int*)(w + off);      off += Npad;
  int*      bsum     = (int*)(w + off);      off += 1024;
  int*      rank     = (int*)(w + off);      off += Epad;
  uint2*    csr      = (uint2*)(w + off);    off += ((size_t)(N_EDGES + 8) * 8 + 255) & ~(size_t)255;
  uint4*    w1bf     = (uint4*)(w + off);    off += (size_t)8192 * 16;        // 128 KB
  unsigned short* h_u16 = (unsigned short*)(w + off); off += (size_t)N_NODES * HID * 2;
  float*    h2       = (float*)(w + off);    off += (size_t)N_NODES * 8 * 4;

  hipMemsetAsync(packed, 0, Npad8, stream);

  k_deg<<<N_EDGES / 256, 256, 0, stream>>>(ei, ew, packed, rank);
  k_mid<<<NB_SCAN + 32, 256, 0, stream>>>(packed, dinv, cnt, bsum, W1, w1bf, csr + N_EDGES);
  k_scan_bsum<<<1, 64, 0, stream>>>(bsum, NB_SCAN);
  k_scan_final<<<NB_SCAN, 256, 0, stream>>>(cnt, bsum, offs);
  k_fill<<<N_EDGES / 256, 256, 0, stream>>>(ei, ew, rank, offs, csr);
  k_gemm1<<<(N_NODES / 16 + 3) / 4, 256, 0, stream>>>(x, w1bf, dinv, h_u16);
  k_agg1<<<(N_NODES + 3) / 4, 256, 0, stream>>>((const unsigned*)h_u16, dinv, offs, cnt,
                                                csr, b1, W2, h2);
  k_agg2<<<(N_NODES + 3) / 4, 256, 0, stream>>>(h2, dinv, offs, cnt, csr, b2, out);
}

// Round 3
// 536.489 us; speedup vs baseline: 1.1956x; 1.1382x over previous
//
#include <hip/hip_runtime.h>
#include <math.h>

#define N_NODES 100000
#define N_EDGES 1600000
#define IN_F 512
#define HID 128
#define NCLS 7

#define DEG_SHIFT 43
#define DEG_WMASK ((1ull << 43) - 1)
#define DEG_SCALE 4194304.0f          // 2^22
#define DEG_INV_SCALE (1.0f / 4194304.0f)
#define NB_SCAN 98                    // ceil(100000 / 1024)

typedef short short8 __attribute__((ext_vector_type(8)));
typedef float f32x4 __attribute__((ext_vector_type(4)));
typedef unsigned long long u64;

__device__ __forceinline__ unsigned pack_bf16x2(float a, float b) {
  unsigned ua = __float_as_uint(a), ub = __float_as_uint(b);
  unsigned ra = (ua + 0x7FFFu + ((ua >> 16) & 1u)) >> 16;     // RNE
  unsigned rb = (ub + 0x7FFFu + ((ub >> 16) & 1u)) >> 16;
  return ra | (rb << 16);
}
__device__ __forceinline__ unsigned short f32_to_bf16(float v) {
  unsigned u = __float_as_uint(v);
  return (unsigned short)((u + 0x7FFFu + ((u >> 16) & 1u)) >> 16);
}
__device__ __forceinline__ float bf_lo(unsigned u) { return __uint_as_float(u << 16); }
__device__ __forceinline__ float bf_hi(unsigned u) { return __uint_as_float(u & 0xFFFF0000u); }

// ---------------- degree + count + rank in ONE u64 atomic per edge ----------------
__global__ void k_deg(const int* __restrict__ ei, const float* __restrict__ ew,
                      unsigned long long* __restrict__ packed, int* __restrict__ rank) {
  int e = blockIdx.x * 256 + threadIdx.x;          // grid exact: N_EDGES % 256 == 0
  int d = ei[N_EDGES + e];
  u64 fx = (u64)(ew[e] * DEG_SCALE + 0.5f);
  u64 old = atomicAdd(&packed[d], (1ull << DEG_SHIFT) | fx);
  rank[e] = (int)(old >> DEG_SHIFT);               // this edge's slot within its dst bucket
}

// ---------------- merged: scan-partial + dinv/cnt  (blocks 0..NB_SCAN-1)  and W1 repack (32 more)
// W1 frag-major bf16 layout: w1bf[(s*8 + t)*64 + lane] (uint4), n = t*16+(lane&15),
// k = s*32 + (lane>>4)*8 + {0..7}. One B fragment = 1 KB fully contiguous, lane-ordered.
__global__ void k_mid(const unsigned long long* __restrict__ packed,
                      float* __restrict__ dinv, int* __restrict__ cnt, int* __restrict__ bsum,
                      const float* __restrict__ W1, uint4* __restrict__ w1bf,
                      uint2* __restrict__ csr_pad) {
  const int b = blockIdx.x, t = threadIdx.x;
  if (b >= NB_SCAN) {                              // ---- W1 repack part ----
    int idx = (b - NB_SCAN) * 256 + t;             // 0..8191
    if (idx < 8) csr_pad[idx] = make_uint2(0u, 0u);  // safe over-read entries (src=0, w=0)
    int lane = idx & 63;
    int st = idx >> 6;
    int tt = st & 7, ss = st >> 3;
    int n = tt * 16 + (lane & 15);
    int k0 = ss * 32 + (lane >> 4) * 8;
    uint4 v;
    v.x = pack_bf16x2(W1[(size_t)(k0 + 0) * HID + n], W1[(size_t)(k0 + 1) * HID + n]);
    v.y = pack_bf16x2(W1[(size_t)(k0 + 2) * HID + n], W1[(size_t)(k0 + 3) * HID + n]);
    v.z = pack_bf16x2(W1[(size_t)(k0 + 4) * HID + n], W1[(size_t)(k0 + 5) * HID + n]);
    v.w = pack_bf16x2(W1[(size_t)(k0 + 6) * HID + n], W1[(size_t)(k0 + 7) * HID + n]);
    w1bf[idx] = v;
    return;
  }
  // ---- dinv + cnt + per-block partial sum ----
  __shared__ int sh[256];
  int base = b * 1024;
  int v = 0;
#pragma unroll
  for (int q = 0; q < 4; q++) {
    int idx = base + t * 4 + q;
    if (idx < N_NODES) {
      unsigned long long p = packed[idx];
      int c = (int)(p >> DEG_SHIFT);
      cnt[idx] = c;
      dinv[idx] = rsqrtf((float)(p & DEG_WMASK) * DEG_INV_SCALE + 1.0f);  // +1 = self-loop
      v += c;
    }
  }
  sh[t] = v;
  __syncthreads();
  for (int o = 128; o > 0; o >>= 1) {
    if (t < o) sh[t] += sh[t + o];
    __syncthreads();
  }
  if (t == 0) bsum[b] = sh[0];
}

__global__ void k_scan_bsum(int* bsum, int nb) {
  if (threadIdx.x == 0 && blockIdx.x == 0) {
    int acc = 0;
    for (int i = 0; i < nb; i++) { int v = bsum[i]; bsum[i] = acc; acc += v; }
  }
}

__global__ void k_scan_final(const int* __restrict__ cnt, const int* __restrict__ bsum,
                             int* __restrict__ offs) {
  __shared__ int s[256];
  int t = threadIdx.x;
  int base = blockIdx.x * 1024;
  int v[4]; int sum = 0;
#pragma unroll
  for (int q = 0; q < 4; q++) {
    int idx = base + t * 4 + q;
    v[q] = (idx < N_NODES) ? cnt[idx] : 0;
    sum += v[q];
  }
  s[t] = sum;
  __syncthreads();
  for (int o = 1; o < 256; o <<= 1) {
    int x = (t >= o) ? s[t - o] : 0;
    __syncthreads();
    s[t] += x;
    __syncthreads();
  }
  int acc = s[t] - sum + bsum[blockIdx.x];
#pragma unroll
  for (int q = 0; q < 4; q++) {
    int idx = base + t * 4 + q;
    if (idx < N_NODES) offs[idx] = acc;
    acc += v[q];
  }
}

// ---------------- CSR fill: NO atomics (rank precomputed); one 8B scatter per edge ----------------
__global__ void k_fill(const int* __restrict__ ei, const float* __restrict__ ew,
                       const int* __restrict__ rank, const int* __restrict__ offs,
                       uint2* __restrict__ csr) {
  int e = blockIdx.x * 256 + threadIdx.x;          // grid exact
  int s = ei[e];
  int d = ei[N_EDGES + e];
  int p = offs[d] + rank[e];
  csr[p] = make_uint2((unsigned)s, __float_as_uint(ew[e]));
}

// ---------------- GEMM1: wave-synchronous, all-contiguous loads, no barriers (r0-proven) --------
// Each wave: M=16 rows, N=128, K=512. 6250 waves total (100000/16 exactly).
// A: per K-half, 16 loads of one contiguous 1KB row-half each -> bf16 -> wave-private LDS.
// B: frag-major w1bf, every fragment = one contiguous 1KB load (L2-resident 128KB).
#define SLABSTRIDE 132   // dwords per LDS row (128 data + 4 pad)
__global__ __launch_bounds__(256) void k_gemm1(const float* __restrict__ x,
                                               const uint4* __restrict__ w1bf,
                                               const float* __restrict__ dinv,
                                               unsigned short* __restrict__ h_u16) {
  __shared__ unsigned slab[4 * 16 * SLABSTRIDE];
  const int tid = threadIdx.x;
  const int lane = tid & 63;
  const int wv = tid >> 6;
  const int gw = blockIdx.x * 4 + wv;          // global wave id
  if (gw >= N_NODES / 16) return;
  const int m0 = gw * 16;
  unsigned* ws = slab + wv * 16 * SLABSTRIDE;  // wave-private slab
  const int l16 = lane & 15, quad = lane >> 4;

  f32x4 acc[8];
#pragma unroll
  for (int t = 0; t < 8; t++) acc[t] = (f32x4){0.f, 0.f, 0.f, 0.f};

#pragma unroll
  for (int hf = 0; hf < 2; hf++) {
    // ---- stage: 16 rows x 256 k, each load = 1KB contiguous ----
#pragma unroll
    for (int b = 0; b < 2; b++) {
      float4 v[8];
#pragma unroll
      for (int i = 0; i < 8; i++) {
        int row = b * 8 + i;
        v[i] = *(const float4*)(x + (size_t)(m0 + row) * IN_F + hf * 256 + lane * 4);
      }
#pragma unroll
      for (int i = 0; i < 8; i++) {
        int row = b * 8 + i;
        unsigned lo = pack_bf16x2(v[i].x, v[i].y);
        unsigned hi = pack_bf16x2(v[i].z, v[i].w);
        *(uint2*)&ws[row * SLABSTRIDE + lane * 2] = make_uint2(lo, hi);
      }
    }
    __threadfence_block();   // wave-local: drain own ds_writes before frag reads
    // ---- compute: 8 k-steps, A frag from LDS, B frags contiguous from global ----
#pragma unroll
    for (int ks = 0; ks < 8; ks++) {
      short8 af = *(const short8*)&ws[l16 * SLABSTRIDE + ks * 16 + quad * 4];
      const uint4* bbase = w1bf + (size_t)(hf * 8 + ks) * 8 * 64 + lane;
#pragma unroll
      for (int t = 0; t < 8; t++) {
        uint4 bv = bbase[t * 64];
        acc[t] = __builtin_amdgcn_mfma_f32_16x16x32_bf16(af, *(const short8*)&bv,
                                                         acc[t], 0, 0, 0);
      }
    }
  }
  // ---- epilogue: C/D row = quad*4+r, col = t*16+l16; scale by dinv[row], store bf16 ----
  float df[4];
#pragma unroll
  for (int r = 0; r < 4; r++) df[r] = dinv[m0 + quad * 4 + r];
#pragma unroll
  for (int t = 0; t < 8; t++)
#pragma unroll
    for (int r = 0; r < 4; r++)
      h_u16[(size_t)(m0 + quad * 4 + r) * HID + t * 16 + l16] = f32_to_bf16(acc[t][r] * df[r]);
}

// ---------------- layer-1 aggregation + ELU + FUSED GEMM2 (act1 never materialized) -------------
// Wave per node, r0-proven gather loop. Lane covers feats [2l, 2l+1]. After ELU, 7 per-lane
// partials vs register W2, 6-step butterfly, lanes 0..7 store the 32 B h2 row (pre-scaled
// by dinv[i], pad col = 0). Saves 51.2 MB act1 traffic + one dispatch vs separate GEMM2.
__global__ __launch_bounds__(256) void k_agg1(const unsigned* __restrict__ h_u,
    const float* __restrict__ dinv, const int* __restrict__ offs, const int* __restrict__ cnt,
    const uint2* __restrict__ csr, const float* __restrict__ b1,
    const float* __restrict__ W2, float* __restrict__ h2) {
  int i = blockIdx.x * 4 + (threadIdx.x >> 6);   // wave -> node
  int lane = threadIdx.x & 63;                   // lane covers feats [2l, 2l+1]
  if (i >= N_NODES) return;
  float w2a[NCLS], w2b[NCLS];                    // 14 floats, L1-resident after warm-up
#pragma unroll
  for (int c = 0; c < NCLS; c++) {
    w2a[c] = W2[(size_t)(2 * lane) * NCLS + c];
    w2b[c] = W2[(size_t)(2 * lane + 1) * NCLS + c];
  }
  int start = offs[i], len = cnt[i];
  int end = start + len;
  float ax = 0.f, ay = 0.f;
  for (int p = start; p < end; p += 8) {
    uint2 e[8];
#pragma unroll
    for (int k = 0; k < 8; k++) e[k] = csr[p + k];   // padded: safe over-read
    unsigned u[8];
#pragma unroll
    for (int k = 0; k < 8; k++) u[k] = h_u[(size_t)e[k].x * 64 + lane];
#pragma unroll
    for (int k = 0; k < 8; k++) {
      float n = (k == 0 || p + k < end) ? __uint_as_float(e[k].y) : 0.f;
      ax = fmaf(bf_lo(u[k]), n, ax);
      ay = fmaf(bf_hi(u[k]), n, ay);
    }
  }
  float di = dinv[i];
  unsigned u = h_u[(size_t)i * 64 + lane];         // self (already * dinv[i])
  float2 bb = *(const float2*)(b1 + lane * 2);
  float vx = fmaf(di, ax + bf_lo(u), bb.x);
  float vy = fmaf(di, ay + bf_hi(u), bb.y);
  vx = vx > 0.f ? vx : expm1f(vx);                 // ELU (alpha=1)
  vy = vy > 0.f ? vy : expm1f(vy);
  // fused GEMM2: h2[i,:] = dinv[i] * (act1[i,:] @ W2)
  float s[NCLS];
#pragma unroll
  for (int c = 0; c < NCLS; c++) s[c] = fmaf(vy, w2b[c], vx * w2a[c]);
#pragma unroll
  for (int m = 1; m < 64; m <<= 1) {
#pragma unroll
    for (int c = 0; c < NCLS; c++) s[c] += __shfl_xor(s[c], m);
  }
  if (lane < 8) {
    float v = lane == 0 ? s[0] : lane == 1 ? s[1] : lane == 2 ? s[2] :
              lane == 3 ? s[3] : lane == 4 ? s[4] : lane == 5 ? s[5] : s[6];
    h2[(size_t)i * 8 + lane] = (lane < NCLS) ? v * di : 0.f;   // pad col = 0
  }
}

// ---------------- layer-2 aggregation + bias + log_softmax (r0-proven 8-lane/node) ----------------
__global__ __launch_bounds__(256) void k_agg2(const float* __restrict__ h2,
    const float* __restrict__ dinv, const int* __restrict__ offs, const int* __restrict__ cnt,
    const uint2* __restrict__ csr, const float* __restrict__ b2, float* __restrict__ out) {
  int tid = threadIdx.x;
  int i = blockIdx.x * 32 + (tid >> 3);   // 8 lanes per node
  int f = tid & 7;                        // f==7 is padding lane
  if (i >= N_NODES) return;
  int start = offs[i], len = cnt[i];
  int end = start + len;
  float acc = 0.0f;
  for (int p = start; p < end; p += 4) {
    uint2 e0 = csr[p];
    uint2 e1 = csr[p + 1];
    uint2 e2 = csr[p + 2];
    uint2 e3 = csr[p + 3];
    float v0 = h2[(size_t)e0.x * 8 + f];
    float v1 = h2[(size_t)e1.x * 8 + f];
    float v2 = h2[(size_t)e2.x * 8 + f];
    float v3 = h2[(size_t)e3.x * 8 + f];
    float n0 = __uint_as_float(e0.y);
    float n1 = (p + 1 < end) ? __uint_as_float(e1.y) : 0.f;
    float n2 = (p + 2 < end) ? __uint_as_float(e2.y) : 0.f;
    float n3 = (p + 3 < end) ? __uint_as_float(e3.y) : 0.f;
    acc = fmaf(v0, n0, acc);
    acc = fmaf(v1, n1, acc);
    acc = fmaf(v2, n2, acc);
    acc = fmaf(v3, n3, acc);
  }
  float di = dinv[i];
  float v = fmaf(di, acc + h2[(size_t)i * 8 + f], (f < NCLS) ? b2[f] : 0.0f);
  float vm = (f < NCLS) ? v : -INFINITY;
#pragma unroll
  for (int o = 1; o < 8; o <<= 1) vm = fmaxf(vm, __shfl_xor(vm, o, 8));
  float ex = (f < NCLS) ? expf(v - vm) : 0.0f;
  float s8 = ex;
#pragma unroll
  for (int o = 1; o < 8; o <<= 1) s8 += __shfl_xor(s8, o, 8);
  float lse = logf(s8);
  if (f < NCLS) out[(size_t)i * NCLS + f] = v - vm - lse;
}

// ---------------- launch ----------------
extern "C" void kernel_launch(void* const* d_in, const int* in_sizes, int n_in,
                              void* d_out, int out_size, void* d_ws, size_t ws_size,
                              hipStream_t stream) {
  const float* x  = (const float*)d_in[0];
  const int*   ei = (const int*)d_in[1];
  const float* ew = (const float*)d_in[2];
  const float* W1 = (const float*)d_in[3];
  const float* b1 = (const float*)d_in[4];
  const float* W2 = (const float*)d_in[5];
  const float* b2 = (const float*)d_in[6];
  float* out = (float*)d_out;

  char* w = (char*)d_ws;
  const size_t Npad  = ((size_t)N_NODES * 4 + 255) & ~(size_t)255;
  const size_t Npad8 = ((size_t)N_NODES * 8 + 255) & ~(size_t)255;
  const size_t Epad  = ((size_t)N_EDGES * 4 + 255) & ~(size_t)255;
  size_t off = 0;
  unsigned long long* packed = (unsigned long long*)(w + off); off += Npad8;  // zeroed
  float*    dinv     = (float*)(w + off);    off += Npad;
  int*      cnt      = (int*)(w + off);      off += Npad;
  int*      offs     = (int*)(w + off);      off += Npad;
  int*      bsum     = (int*)(w + off);      off += 1024;
  int*      rank     = (int*)(w + off);      off += Epad;
  uint2*    csr      = (uint2*)(w + off);    off += ((size_t)(N_EDGES + 8) * 8 + 255) & ~(size_t)255;
  uint4*    w1bf     = (uint4*)(w + off);    off += (size_t)8192 * 16;        // 128 KB
  unsigned short* h_u16 = (unsigned short*)(w + off); off += (size_t)N_NODES * HID * 2;
  float*    h2       = (float*)(w + off);    off += (size_t)N_NODES * 8 * 4;

  hipMemsetAsync(packed, 0, Npad8, stream);

  k_deg<<<N_EDGES / 256, 256, 0, stream>>>(ei, ew, packed, rank);
  k_mid<<<NB_SCAN + 32, 256, 0, stream>>>(packed, dinv, cnt, bsum, W1, w1bf, csr + N_EDGES);
  k_scan_bsum<<<1, 64, 0, stream>>>(bsum, NB_SCAN);
  k_scan_final<<<NB_SCAN, 256, 0, stream>>>(cnt, bsum, offs);
  k_fill<<<N_EDGES / 256, 256, 0, stream>>>(ei, ew, rank, offs, csr);
  k_gemm1<<<(N_NODES / 16 + 3) / 4, 256, 0, stream>>>(x, w1bf, dinv, h_u16);
  k_agg1<<<(N_NODES + 3) / 4, 256, 0, stream>>>((const unsigned*)h_u16, dinv, offs, cnt,
                                                csr, b1, W2, h2);
  k_agg2<<<N_NODES / 32, 256, 0, stream>>>(h2, dinv, offs, cnt, csr, b2, out);
}

// Round 4
// 505.659 us; speedup vs baseline: 1.2685x; 1.0610x over previous
//
#include <hip/hip_runtime.h>
#include <math.h>

#define N_NODES 100000
#define N_EDGES 1600000
#define IN_F 512
#define HID 128
#define NCLS 7

#define DEG_SHIFT 43
#define DEG_WMASK ((1ull << 43) - 1)
#define DEG_SCALE 4194304.0f          // 2^22
#define DEG_INV_SCALE (1.0f / 4194304.0f)
#define NB_SCAN 98                    // ceil(100000 / 1024)
#define G_FILL 6250                   // N_EDGES / 256
#define G_GEMM 1563                   // ceil((N_NODES/16) / 4) waves-blocks
#define G_MERGED (G_FILL + G_GEMM)    // 7813

typedef short short8 __attribute__((ext_vector_type(8)));
typedef float f32x4 __attribute__((ext_vector_type(4)));
typedef unsigned long long u64;

__device__ __forceinline__ unsigned pack_bf16x2(float a, float b) {
  unsigned ua = __float_as_uint(a), ub = __float_as_uint(b);
  unsigned ra = (ua + 0x7FFFu + ((ua >> 16) & 1u)) >> 16;     // RNE
  unsigned rb = (ub + 0x7FFFu + ((ub >> 16) & 1u)) >> 16;
  return ra | (rb << 16);
}
__device__ __forceinline__ unsigned short f32_to_bf16(float v) {
  unsigned u = __float_as_uint(v);
  return (unsigned short)((u + 0x7FFFu + ((u >> 16) & 1u)) >> 16);
}
__device__ __forceinline__ float bf_lo(unsigned u) { return __uint_as_float(u << 16); }
__device__ __forceinline__ float bf_hi(unsigned u) { return __uint_as_float(u & 0xFFFF0000u); }

// ---------------- degree + count + rank in ONE u64 atomic per edge ----------------
__global__ void k_deg(const int* __restrict__ ei, const float* __restrict__ ew,
                      unsigned long long* __restrict__ packed, int* __restrict__ rank) {
  int e = blockIdx.x * 256 + threadIdx.x;          // grid exact: N_EDGES % 256 == 0
  int d = ei[N_EDGES + e];
  u64 fx = (u64)(ew[e] * DEG_SCALE + 0.5f);
  u64 old = atomicAdd(&packed[d], (1ull << DEG_SHIFT) | fx);
  rank[e] = (int)(old >> DEG_SHIFT);               // this edge's slot within its dst bucket
}

// ---------------- merged: scan-partial + dinv/cnt  (blocks 0..NB_SCAN-1)  and W1 repack (32 more)
// W1 frag-major bf16 layout: w1bf[(s*8 + t)*64 + lane] (uint4), n = t*16+(lane&15),
// k = s*32 + (lane>>4)*8 + {0..7}. One B fragment = 1 KB fully contiguous, lane-ordered.
__global__ void k_mid(const unsigned long long* __restrict__ packed,
                      float* __restrict__ dinv, int* __restrict__ cnt, int* __restrict__ bsum,
                      const float* __restrict__ W1, uint4* __restrict__ w1bf,
                      uint2* __restrict__ csr_pad) {
  const int b = blockIdx.x, t = threadIdx.x;
  if (b >= NB_SCAN) {                              // ---- W1 repack part ----
    int idx = (b - NB_SCAN) * 256 + t;             // 0..8191
    if (idx < 8) csr_pad[idx] = make_uint2(0u, 0u);  // safe over-read entries (src=0, w=0)
    int lane = idx & 63;
    int st = idx >> 6;
    int tt = st & 7, ss = st >> 3;
    int n = tt * 16 + (lane & 15);
    int k0 = ss * 32 + (lane >> 4) * 8;
    uint4 v;
    v.x = pack_bf16x2(W1[(size_t)(k0 + 0) * HID + n], W1[(size_t)(k0 + 1) * HID + n]);
    v.y = pack_bf16x2(W1[(size_t)(k0 + 2) * HID + n], W1[(size_t)(k0 + 3) * HID + n]);
    v.z = pack_bf16x2(W1[(size_t)(k0 + 4) * HID + n], W1[(size_t)(k0 + 5) * HID + n]);
    v.w = pack_bf16x2(W1[(size_t)(k0 + 6) * HID + n], W1[(size_t)(k0 + 7) * HID + n]);
    w1bf[idx] = v;
    return;
  }
  // ---- dinv + cnt + per-block partial sum ----
  __shared__ int sh[256];
  int base = b * 1024;
  int v = 0;
#pragma unroll
  for (int q = 0; q < 4; q++) {
    int idx = base + t * 4 + q;
    if (idx < N_NODES) {
      unsigned long long p = packed[idx];
      int c = (int)(p >> DEG_SHIFT);
      cnt[idx] = c;
      dinv[idx] = rsqrtf((float)(p & DEG_WMASK) * DEG_INV_SCALE + 1.0f);  // +1 = self-loop
      v += c;
    }
  }
  sh[t] = v;
  __syncthreads();
  for (int o = 128; o > 0; o >>= 1) {
    if (t < o) sh[t] += sh[t + o];
    __syncthreads();
  }
  if (t == 0) bsum[b] = sh[0];
}

// ---------------- scan-final with FOLDED bsum prefix (serial k_scan_bsum eliminated) -----------
// Each block reduces bsum[j < blockIdx.x] itself: 98 parallel loads + LDS tree, ~1 us,
// replacing a single-thread serial kernel + one launch gap.
__global__ void k_scan_final(const int* __restrict__ cnt, const int* __restrict__ bsum,
                             int* __restrict__ offs) {
  __shared__ int s[256];
  int t = threadIdx.x;
  // block offset = sum of bsum[j] for j < blockIdx.x
  int c = (t < NB_SCAN && t < blockIdx.x) ? bsum[t] : 0;
  s[t] = c;
  __syncthreads();
  for (int o = 128; o > 0; o >>= 1) {
    if (t < o) s[t] += s[t + o];
    __syncthreads();
  }
  int block_off = s[0];
  __syncthreads();
  // per-block exclusive scan of cnt (4 elems/thread)
  int base = blockIdx.x * 1024;
  int v[4]; int sum = 0;
#pragma unroll
  for (int q = 0; q < 4; q++) {
    int idx = base + t * 4 + q;
    v[q] = (idx < N_NODES) ? cnt[idx] : 0;
    sum += v[q];
  }
  s[t] = sum;
  __syncthreads();
  for (int o = 1; o < 256; o <<= 1) {
    int x = (t >= o) ? s[t - o] : 0;
    __syncthreads();
    s[t] += x;
    __syncthreads();
  }
  int acc = s[t] - sum + block_off;
#pragma unroll
  for (int q = 0; q < 4; q++) {
    int idx = base + t * 4 + q;
    if (idx < N_NODES) offs[idx] = acc;
    acc += v[q];
  }
}

// ---------------- MERGED fill + GEMM1 in one dispatch (independent, complementary pipes) -------
// Every 5th block (bx%5==0, 1563 of them) is a GEMM block; the other 6250 are fill blocks.
// fill: scatter-bound, ~zero VALU/MFMA. gemm: MFMA + L2-read-bound. Co-scheduling hides
// fill's time under gemm instead of serializing the two dispatches.
//
// GEMM1 (r3-proven): wave = 16 rows x 128 cols, K=512. 6250 waves total.
// A: per K-half, 16 contiguous 1KB row-half loads -> bf16 -> wave-private LDS.
// B: frag-major w1bf, every fragment = one contiguous 1KB load (L2-resident 128KB).
#define SLABSTRIDE 132   // dwords per LDS row (128 data + 4 pad)
__global__ __launch_bounds__(256) void k_fillgemm(
    const int* __restrict__ ei, const float* __restrict__ ew,
    const int* __restrict__ rank, const int* __restrict__ offs, uint2* __restrict__ csr,
    const float* __restrict__ x, const uint4* __restrict__ w1bf,
    const float* __restrict__ dinv, unsigned short* __restrict__ h_u16) {
  __shared__ unsigned slab[4 * 16 * SLABSTRIDE];
  const int bx = blockIdx.x;
  const int tid = threadIdx.x;

  if (bx % 5 != 0) {
    // ---------------- fill role: one 8B scatter per edge, no atomics ----------------
    int fb = bx - bx / 5 - 1;                      // 0..6249, bijective over non-multiples of 5
    int e = fb * 256 + tid;
    int s = ei[e];
    int d = ei[N_EDGES + e];
    int p = offs[d] + rank[e];
    csr[p] = make_uint2((unsigned)s, __float_as_uint(ew[e]));
    return;
  }

  // ---------------- gemm role ----------------
  const int gb = bx / 5;                           // 0..1562
  const int lane = tid & 63;
  const int wv = tid >> 6;
  const int gw = gb * 4 + wv;                      // global wave id
  if (gw >= N_NODES / 16) return;
  const int m0 = gw * 16;
  unsigned* ws = slab + wv * 16 * SLABSTRIDE;      // wave-private slab
  const int l16 = lane & 15, quad = lane >> 4;

  f32x4 acc[8];
#pragma unroll
  for (int t = 0; t < 8; t++) acc[t] = (f32x4){0.f, 0.f, 0.f, 0.f};

#pragma unroll
  for (int hf = 0; hf < 2; hf++) {
    // ---- stage: 16 rows x 256 k, each load = 1KB contiguous ----
#pragma unroll
    for (int b = 0; b < 2; b++) {
      float4 v[8];
#pragma unroll
      for (int i = 0; i < 8; i++) {
        int row = b * 8 + i;
        v[i] = *(const float4*)(x + (size_t)(m0 + row) * IN_F + hf * 256 + lane * 4);
      }
#pragma unroll
      for (int i = 0; i < 8; i++) {
        int row = b * 8 + i;
        unsigned lo = pack_bf16x2(v[i].x, v[i].y);
        unsigned hi = pack_bf16x2(v[i].z, v[i].w);
        *(uint2*)&ws[row * SLABSTRIDE + lane * 2] = make_uint2(lo, hi);
      }
    }
    __threadfence_block();   // wave-local: drain own ds_writes before frag reads
    // ---- compute: 8 k-steps, A frag from LDS, B frags contiguous from global ----
#pragma unroll
    for (int ks = 0; ks < 8; ks++) {
      short8 af = *(const short8*)&ws[l16 * SLABSTRIDE + ks * 16 + quad * 4];
      const uint4* bbase = w1bf + (size_t)(hf * 8 + ks) * 8 * 64 + lane;
#pragma unroll
      for (int t = 0; t < 8; t++) {
        uint4 bv = bbase[t * 64];
        acc[t] = __builtin_amdgcn_mfma_f32_16x16x32_bf16(af, *(const short8*)&bv,
                                                         acc[t], 0, 0, 0);
      }
    }
  }
  // ---- epilogue: C/D row = quad*4+r, col = t*16+l16; scale by dinv[row], store bf16 ----
  float df[4];
#pragma unroll
  for (int r = 0; r < 4; r++) df[r] = dinv[m0 + quad * 4 + r];
#pragma unroll
  for (int t = 0; t < 8; t++)
#pragma unroll
    for (int r = 0; r < 4; r++)
      h_u16[(size_t)(m0 + quad * 4 + r) * HID + t * 16 + l16] = f32_to_bf16(acc[t][r] * df[r]);
}

// ---------------- layer-1 aggregation + ELU + FUSED GEMM2 (act1 never materialized) -------------
// Wave per node. Lane covers feats [2l, 2l+1]. After ELU, 7 per-lane partials vs register W2,
// 6-step butterfly, lanes 0..7 store the 32 B h2 row (pre-scaled by dinv[i], pad col = 0).
__global__ __launch_bounds__(256) void k_agg1(const unsigned* __restrict__ h_u,
    const float* __restrict__ dinv, const int* __restrict__ offs, const int* __restrict__ cnt,
    const uint2* __restrict__ csr, const float* __restrict__ b1,
    const float* __restrict__ W2, float* __restrict__ h2) {
  int i = blockIdx.x * 4 + (threadIdx.x >> 6);   // wave -> node
  int lane = threadIdx.x & 63;                   // lane covers feats [2l, 2l+1]
  if (i >= N_NODES) return;
  float w2a[NCLS], w2b[NCLS];                    // 14 floats, L1-resident after warm-up
#pragma unroll
  for (int c = 0; c < NCLS; c++) {
    w2a[c] = W2[(size_t)(2 * lane) * NCLS + c];
    w2b[c] = W2[(size_t)(2 * lane + 1) * NCLS + c];
  }
  int start = offs[i], len = cnt[i];
  int end = start + len;
  float ax = 0.f, ay = 0.f;
  for (int p = start; p < end; p += 8) {
    uint2 e[8];
#pragma unroll
    for (int k = 0; k < 8; k++) e[k] = csr[p + k];   // padded: safe over-read
    unsigned u[8];
#pragma unroll
    for (int k = 0; k < 8; k++) u[k] = h_u[(size_t)e[k].x * 64 + lane];
#pragma unroll
    for (int k = 0; k < 8; k++) {
      float n = (k == 0 || p + k < end) ? __uint_as_float(e[k].y) : 0.f;
      ax = fmaf(bf_lo(u[k]), n, ax);
      ay = fmaf(bf_hi(u[k]), n, ay);
    }
  }
  float di = dinv[i];
  unsigned u = h_u[(size_t)i * 64 + lane];         // self (already * dinv[i])
  float2 bb = *(const float2*)(b1 + lane * 2);
  float vx = fmaf(di, ax + bf_lo(u), bb.x);
  float vy = fmaf(di, ay + bf_hi(u), bb.y);
  vx = vx > 0.f ? vx : expm1f(vx);                 // ELU (alpha=1)
  vy = vy > 0.f ? vy : expm1f(vy);
  // fused GEMM2: h2[i,:] = dinv[i] * (act1[i,:] @ W2)
  float s[NCLS];
#pragma unroll
  for (int c = 0; c < NCLS; c++) s[c] = fmaf(vy, w2b[c], vx * w2a[c]);
#pragma unroll
  for (int m = 1; m < 64; m <<= 1) {
#pragma unroll
    for (int c = 0; c < NCLS; c++) s[c] += __shfl_xor(s[c], m);
  }
  if (lane < 8) {
    float v = lane == 0 ? s[0] : lane == 1 ? s[1] : lane == 2 ? s[2] :
              lane == 3 ? s[3] : lane == 4 ? s[4] : lane == 5 ? s[5] : s[6];
    h2[(size_t)i * 8 + lane] = (lane < NCLS) ? v * di : 0.f;   // pad col = 0
  }
}

// ---------------- layer-2 aggregation + bias + log_softmax (r0-proven 8-lane/node) ----------------
__global__ __launch_bounds__(256) void k_agg2(const float* __restrict__ h2,
    const float* __restrict__ dinv, const int* __restrict__ offs, const int* __restrict__ cnt,
    const uint2* __restrict__ csr, const float* __restrict__ b2, float* __restrict__ out) {
  int tid = threadIdx.x;
  int i = blockIdx.x * 32 + (tid >> 3);   // 8 lanes per node
  int f = tid & 7;                        // f==7 is padding lane
  if (i >= N_NODES) return;
  int start = offs[i], len = cnt[i];
  int end = start + len;
  float acc = 0.0f;
  for (int p = start; p < end; p += 4) {
    uint2 e0 = csr[p];
    uint2 e1 = csr[p + 1];
    uint2 e2 = csr[p + 2];
    uint2 e3 = csr[p + 3];
    float v0 = h2[(size_t)e0.x * 8 + f];
    float v1 = h2[(size_t)e1.x * 8 + f];
    float v2 = h2[(size_t)e2.x * 8 + f];
    float v3 = h2[(size_t)e3.x * 8 + f];
    float n0 = __uint_as_float(e0.y);
    float n1 = (p + 1 < end) ? __uint_as_float(e1.y) : 0.f;
    float n2 = (p + 2 < end) ? __uint_as_float(e2.y) : 0.f;
    float n3 = (p + 3 < end) ? __uint_as_float(e3.y) : 0.f;
    acc = fmaf(v0, n0, acc);
    acc = fmaf(v1, n1, acc);
    acc = fmaf(v2, n2, acc);
    acc = fmaf(v3, n3, acc);
  }
  float di = dinv[i];
  float v = fmaf(di, acc + h2[(size_t)i * 8 + f], (f < NCLS) ? b2[f] : 0.0f);
  float vm = (f < NCLS) ? v : -INFINITY;
#pragma unroll
  for (int o = 1; o < 8; o <<= 1) vm = fmaxf(vm, __shfl_xor(vm, o, 8));
  float ex = (f < NCLS) ? expf(v - vm) : 0.0f;
  float s8 = ex;
#pragma unroll
  for (int o = 1; o < 8; o <<= 1) s8 += __shfl_xor(s8, o, 8);
  float lse = logf(s8);
  if (f < NCLS) out[(size_t)i * NCLS + f] = v - vm - lse;
}

// ---------------- launch ----------------
extern "C" void kernel_launch(void* const* d_in, const int* in_sizes, int n_in,
                              void* d_out, int out_size, void* d_ws, size_t ws_size,
                              hipStream_t stream) {
  const float* x  = (const float*)d_in[0];
  const int*   ei = (const int*)d_in[1];
  const float* ew = (const float*)d_in[2];
  const float* W1 = (const float*)d_in[3];
  const float* b1 = (const float*)d_in[4];
  const float* W2 = (const float*)d_in[5];
  const float* b2 = (const float*)d_in[6];
  float* out = (float*)d_out;

  char* w = (char*)d_ws;
  const size_t Npad  = ((size_t)N_NODES * 4 + 255) & ~(size_t)255;
  const size_t Npad8 = ((size_t)N_NODES * 8 + 255) & ~(size_t)255;
  const size_t Epad  = ((size_t)N_EDGES * 4 + 255) & ~(size_t)255;
  size_t off = 0;
  unsigned long long* packed = (unsigned long long*)(w + off); off += Npad8;  // zeroed
  float*    dinv     = (float*)(w + off);    off += Npad;
  int*      cnt      = (int*)(w + off);      off += Npad;
  int*      offs     = (int*)(w + off);      off += Npad;
  int*      bsum     = (int*)(w + off);      off += 1024;
  int*      rank     = (int*)(w + off);      off += Epad;
  uint2*    csr      = (uint2*)(w + off);    off += ((size_t)(N_EDGES + 8) * 8 + 255) & ~(size_t)255;
  uint4*    w1bf     = (uint4*)(w + off);    off += (size_t)8192 * 16;        // 128 KB
  unsigned short* h_u16 = (unsigned short*)(w + off); off += (size_t)N_NODES * HID * 2;
  float*    h2       = (float*)(w + off);    off += (size_t)N_NODES * 8 * 4;

  hipMemsetAsync(packed, 0, Npad8, stream);

  k_deg<<<N_EDGES / 256, 256, 0, stream>>>(ei, ew, packed, rank);
  k_mid<<<NB_SCAN + 32, 256, 0, stream>>>(packed, dinv, cnt, bsum, W1, w1bf, csr + N_EDGES);
  k_scan_final<<<NB_SCAN, 256, 0, stream>>>(cnt, bsum, offs);
  k_fillgemm<<<G_MERGED, 256, 0, stream>>>(ei, ew, rank, offs, csr, x, w1bf, dinv, h_u16);
  k_agg1<<<(N_NODES + 3) / 4, 256, 0, stream>>>((const unsigned*)h_u16, dinv, offs, cnt,
                                                csr, b1, W2, h2);
  k_agg2<<<N_NODES / 32, 256, 0, stream>>>(h2, dinv, offs, cnt, csr, b2, out);
}